// Round 7
// baseline (959.319 us; speedup 1.0000x reference)
//
#include <hip/hip_runtime.h>
#include <hip/hip_bf16.h>

#define N_TOK 32768
#define DIM   512
#define NE    2048

#define IDX_OFF  (N_TOK * DIM)
#define LOSS_OFF (IDX_OFF + N_TOK)
#define PERP_OFF (LOSS_OFF + 1)

#define KB(x) ((size_t)(x) << 10)
#define EPS 4e-4f
#define ENTRY_CAP (1u << 18)

typedef __attribute__((ext_vector_type(8))) short bf16x8;
typedef __attribute__((ext_vector_type(4))) float f32x4;

__device__ inline unsigned short f2bf(float f) {
  unsigned int x = __float_as_uint(f);
  x = x + 0x7fffu + ((x >> 16) & 1u);
  return (unsigned short)(x >> 16);
}
__device__ inline float bfround(float f) {
  return __uint_as_float((unsigned int)f2bf(f) << 16);
}

__global__ void init_kernel(int* counts, float* loss,
                            unsigned long long* tokkey, unsigned* cnt) {
  int g = blockIdx.x * 256 + threadIdx.x;
  for (int i = g; i < NE; i += gridDim.x * 256) counts[i] = 0;
  for (int i = g; i < N_TOK; i += gridDim.x * 256) tokkey[i] = 0xFFFFFFFFFFFFFFFFull;
  if (g == 0) { *loss = 0.f; *cnt = 0u; }
}

// np.sum(x*x, axis=1) exact replication (validated round 4) — do not touch.
__global__ __launch_bounds__(256) void npsum_sq(const float* __restrict__ x,
                                                float* __restrict__ out, int nrows) {
#pragma clang fp contract(off)
  int wave = threadIdx.x >> 6;
  int lane = threadIdx.x & 63;
  int grp = lane >> 4, l = lane & 15;
  int row = blockIdx.x * 16 + wave * 4 + grp;
  if (row >= nrows) return;
  const float* a = x + (size_t)row * DIM;
  float L[4];
  #pragma unroll
  for (int b = 0; b < 4; ++b) {
    const float* p = a + b * 128 + l;
    float q[8];
    #pragma unroll
    for (int j = 0; j < 8; ++j) {
      float t = p[16 * j];
      float s = t * t;
      asm volatile("" : "+v"(s));
      q[j] = s;
    }
    float v = ((q[0] + q[1]) + (q[2] + q[3])) + ((q[4] + q[5]) + (q[6] + q[7]));
    v += __shfl_xor(v, 8);
    v += __shfl_xor(v, 4);
    v += __shfl_xor(v, 2);
    v += __shfl_xor(v, 1);
    L[b] = v;
  }
  if (l == 0) out[row] = (L[0] + L[1]) + (L[2] + L[3]);
}

__global__ __launch_bounds__(256) void cvt_bf(const float* __restrict__ x,
                                              unsigned short* __restrict__ xbf) {
  size_t g = ((size_t)blockIdx.x * 256 + threadIdx.x) * 8;
  float4 a = *(const float4*)(x + g);
  float4 b = *(const float4*)(x + g + 4);
  unsigned short h[8] = {f2bf(a.x), f2bf(a.y), f2bf(a.z), f2bf(a.w),
                         f2bf(b.x), f2bf(b.y), f2bf(b.z), f2bf(b.w)};
  *(uint4*)(xbf + g) = *(uint4*)h;
}

// Stage a 128x64-bf16 tile (16KB) into LDS via global_load_lds width 16.
// LDS dest linear; global source pre-swizzled: slot' = (l&7)^(l>>3) so that
// ds_read at phys slot = logical^(row&7) is bank-conflict-free (involution).
__device__ inline void stage_tile(const unsigned short* __restrict__ gsrc,
                                  unsigned short* lds_base, int w, int l) {
  const int swz_col = ((l & 7) ^ (l >> 3)) * 8;   // elements
  const int rsub = l >> 3;
  #pragma unroll
  for (int s4 = 0; s4 < 4; ++s4) {
    int s = w * 4 + s4;
    const unsigned short* g = gsrc + (size_t)(s * 8 + rsub) * DIM + swz_col;
    __builtin_amdgcn_global_load_lds(
        (const __attribute__((address_space(1))) unsigned int*)g,
        (__attribute__((address_space(3))) unsigned int*)(lds_base + s * 512),
        16, 0, 0);
  }
}

// MFMA GEMM, one pass. Block = 128 codes (A, from ebf) x 128 tokens (B, zbf),
// K=512 in 8 steps of 64, double-buffered LDS + 2-phase schedule.
// Epilogue: val = esum[code] - 2*dot; per-16-code-group min -> groupmin[token][g].
// MFMA chunk order (k=0,32,...,480) identical to validated round 6.
__global__ __launch_bounds__(256, 2) void gemm_groupmin(
    const unsigned short* __restrict__ ebf, const unsigned short* __restrict__ zbf,
    const float* __restrict__ esum, float* __restrict__ groupmin) {
  __shared__ unsigned short smem[2 * 16384];   // [buf][A 8192 | B 8192], 64KB

  const int tid = threadIdx.x;
  const int cb = blockIdx.x;   // code block (16)
  const int tb = blockIdx.y;   // token block (256)
  const int w = tid >> 6, l = tid & 63;
  const int lr = l & 15, lk = l >> 4;
  const int wrow = (w >> 1) * 64;   // code side
  const int wcol = (w & 1) * 64;    // token side

  // esum values for this lane's 16 output rows (codes)
  float esr[4][4];
  #pragma unroll
  for (int i = 0; i < 4; ++i)
    #pragma unroll
    for (int q = 0; q < 4; ++q)
      esr[i][q] = esum[cb * 128 + wrow + i * 16 + lk * 4 + q];

  f32x4 acc[4][4];
  #pragma unroll
  for (int i = 0; i < 4; ++i)
    #pragma unroll
    for (int j = 0; j < 4; ++j) acc[i][j] = (f32x4)(0.f);

  const unsigned short* Ag = ebf + (size_t)(cb * 128) * DIM;
  const unsigned short* Bg = zbf + (size_t)(tb * 128) * DIM;

  // prologue: stage K-tile 0 into buf 0
  stage_tile(Ag, &smem[0], w, l);
  stage_tile(Bg, &smem[8192], w, l);
  asm volatile("s_waitcnt vmcnt(0)" ::: "memory");
  __syncthreads();

  for (int kt = 0; kt < 8; ++kt) {
    const int cur = kt & 1;
    if (kt < 7) {   // issue next-tile stage before compute
      stage_tile(Ag + (kt + 1) * 64, &smem[(cur ^ 1) * 16384], w, l);
      stage_tile(Bg + (kt + 1) * 64, &smem[(cur ^ 1) * 16384 + 8192], w, l);
    }
    const unsigned short* Ab = &smem[cur * 16384];
    const unsigned short* Bb = Ab + 8192;
    #pragma unroll
    for (int ks = 0; ks < 2; ++ks) {
      bf16x8 a[4], b[4];
      #pragma unroll
      for (int i = 0; i < 4; ++i) {
        int row = wrow + i * 16 + lr;
        a[i] = *(const bf16x8*)&Ab[row * 64 + (((ks * 4 + lk) ^ (lr & 7)) * 8)];
      }
      #pragma unroll
      for (int j = 0; j < 4; ++j) {
        int row = wcol + j * 16 + lr;
        b[j] = *(const bf16x8*)&Bb[row * 64 + (((ks * 4 + lk) ^ (lr & 7)) * 8)];
      }
      #pragma unroll
      for (int i = 0; i < 4; ++i)
        #pragma unroll
        for (int j = 0; j < 4; ++j)
          acc[i][j] = __builtin_amdgcn_mfma_f32_16x16x32_bf16(a[i], b[j], acc[i][j], 0, 0, 0);
    }
    if (kt < 7) {
      asm volatile("s_waitcnt vmcnt(0)" ::: "memory");
      __syncthreads();
    }
  }

  // epilogue: group = 16 codes = rows of frag i; min over (q, lk) then lanes lk==0 store
  #pragma unroll
  for (int i = 0; i < 4; ++i) {
    const int g = cb * 8 + (wrow >> 4) + i;
    #pragma unroll
    for (int j = 0; j < 4; ++j) {
      float v0 = fmaf(-2.f, acc[i][j][0], esr[i][0]);
      float v1 = fmaf(-2.f, acc[i][j][1], esr[i][1]);
      float v2 = fmaf(-2.f, acc[i][j][2], esr[i][2]);
      float v3 = fmaf(-2.f, acc[i][j][3], esr[i][3]);
      float m = fminf(fminf(v0, v1), fminf(v2, v3));
      m = fminf(m, __shfl_xor(m, 16));
      m = fminf(m, __shfl_xor(m, 32));
      if (lk == 0) {
        int token = tb * 128 + wcol + j * 16 + lr;
        groupmin[(size_t)token * 128 + g] = m;
      }
    }
  }
}

// Per token: global min over 128 group minima; emit groups within EPS.
__global__ __launch_bounds__(256) void reduce_groups(
    const float* __restrict__ groupmin, unsigned* __restrict__ entries,
    unsigned* __restrict__ cnt) {
  int t = blockIdx.x * 4 + (threadIdx.x >> 6);
  int l = threadIdx.x & 63;
  float g0 = groupmin[(size_t)t * 128 + l];
  float g1 = groupmin[(size_t)t * 128 + 64 + l];
  float m = fminf(g0, g1);
  #pragma unroll
  for (int s = 32; s >= 1; s >>= 1) m = fminf(m, __shfl_xor(m, s));
  float lim = m + EPS;
  if (g0 <= lim) {
    unsigned p = atomicAdd(cnt, 1u);
    if (p < ENTRY_CAP) entries[p] = ((unsigned)t << 7) | (unsigned)l;
  }
  if (g1 <= lim) {
    unsigned p = atomicAdd(cnt, 1u);
    if (p < ENTRY_CAP) entries[p] = ((unsigned)t << 7) | (unsigned)(64 + l);
  }
}

// Exact np-replica rescan: 16 codes per candidate group, sequential fmaf chain
// (validated round 4); winner via 64-bit key atomicMin (tie -> smaller code).
__global__ __launch_bounds__(256) void rescan16(
    const float* __restrict__ z, const float* __restrict__ e,
    const float* __restrict__ zsum, const float* __restrict__ esum,
    const unsigned* __restrict__ entries, const unsigned* __restrict__ cnt,
    unsigned long long* __restrict__ tokkey) {
  unsigned n = *cnt; if (n > ENTRY_CAP) n = ENTRY_CAP;
  unsigned total = n * 16u;
  for (unsigned idx = blockIdx.x * 256 + threadIdx.x; idx < total;
       idx += gridDim.x * 256) {
    unsigned ent = entries[idx >> 4];
    int t = (int)(ent >> 7);
    int c = (int)((ent & 127u) * 16 + (idx & 15u));
    const float* zr = z + (size_t)t * DIM;
    const float* er = e + (size_t)c * DIM;
    float acc = 0.f;
    for (int k = 0; k < DIM; k += 4) {
      float4 zv = *(const float4*)(zr + k);
      float4 ev = *(const float4*)(er + k);
      acc = fmaf(zv.x, ev.x, acc);
      acc = fmaf(zv.y, ev.y, acc);
      acc = fmaf(zv.z, ev.z, acc);
      acc = fmaf(zv.w, ev.w, acc);
    }
    float s = zsum[t] + esum[c];
    float d = s - 2.f * acc;
    unsigned long long key = ((unsigned long long)__float_as_uint(d) << 32) |
                             (unsigned long long)c;
    atomicMin(&tokkey[t], key);
  }
}

__global__ __launch_bounds__(256) void writeout(
    const unsigned long long* __restrict__ tokkey, int* __restrict__ idx_final,
    int* __restrict__ counts, float* __restrict__ out) {
  int t = blockIdx.x * 256 + threadIdx.x;
  int c = (int)(tokkey[t] & (unsigned long long)(NE - 1));
  idx_final[t] = c;
  out[IDX_OFF + t] = bfround((float)c);
  atomicAdd(&counts[c], 1);
}

__global__ __launch_bounds__(256) void gather_loss(
    const float* __restrict__ z, const float* __restrict__ e,
    const int* __restrict__ idx_final, float* __restrict__ out,
    float* __restrict__ loss) {
  int t = blockIdx.x * 8 + (threadIdx.x >> 5);
  int g = threadIdx.x & 31;
  int idx = idx_final[t] & (NE - 1);
  const float* zr = z + (size_t)t * DIM;
  const float* er = e + (size_t)idx * DIM;
  float* op = out + (size_t)t * DIM;
  float s = 0.f;
  #pragma unroll
  for (int p = 0; p < 4; ++p) {
    int c = p * 128 + g * 4;
    float4 ev = *(const float4*)(er + c);
    float4 zv = *(const float4*)(zr + c);
    float4 ov;
    ov.x = bfround(ev.x); ov.y = bfround(ev.y);
    ov.z = bfround(ev.z); ov.w = bfround(ev.w);
    *(float4*)(op + c) = ov;
    float dx = ev.x - zv.x, dy = ev.y - zv.y, dz2 = ev.z - zv.z, dw = ev.w - zv.w;
    s += dx*dx + dy*dy + dz2*dz2 + dw*dw;
  }
  #pragma unroll
  for (int m = 32; m >= 1; m >>= 1) s += __shfl_xor(s, m);
  if ((threadIdx.x & 63) == 0) atomicAdd(loss, s);
}

__global__ void finalize_kernel(const int* __restrict__ counts,
                                const float* __restrict__ loss,
                                float* __restrict__ out) {
  __shared__ float red[4];
  int tid = threadIdx.x;
  float s = 0.f;
  for (int j = tid; j < NE; j += 256) {
    float p = (float)counts[j] * (1.0f / (float)N_TOK);
    s += p * logf(p + 1e-10f);
  }
  #pragma unroll
  for (int m = 32; m >= 1; m >>= 1) s += __shfl_xor(s, m);
  if ((tid & 63) == 0) red[tid >> 6] = s;
  __syncthreads();
  if (tid == 0) {
    float tot = red[0] + red[1] + red[2] + red[3];
    out[PERP_OFF] = bfround(expf(-tot));
    out[LOSS_OFF] = bfround(loss[0] * 1.25f / (float)(N_TOK * DIM));
  }
}

extern "C" void kernel_launch(void* const* d_in, const int* in_sizes, int n_in,
                              void* d_out, int out_size, void* d_ws, size_t ws_size,
                              hipStream_t stream) {
  const float* z = (const float*)d_in[0];
  const float* e = (const float*)d_in[1];
  float* out = (float*)d_out;
  char* ws = (char*)d_ws;

  // workspace (~3.6 MB, under proven budget)
  float*    zsum      = (float*)(ws + KB(0));      // 128 KB
  float*    esum      = (float*)(ws + KB(128));    // 8 KB
  int*      counts    = (int*)(ws + KB(136));      // 8 KB
  float*    loss      = (float*)(ws + KB(144));
  unsigned* cnt       = (unsigned*)(ws + KB(148));
  int*      idx_final = (int*)(ws + KB(152));      // 128 KB
  unsigned long long* tokkey = (unsigned long long*)(ws + KB(280)); // 256 KB
  unsigned* entries   = (unsigned*)(ws + KB(536)); // 1 MB
  unsigned short* ebf = (unsigned short*)(ws + KB(1560)); // 2 MB

  // big scratch parked in d_out (overwritten by gather_loss at the end):
  // zbf (32 MB) = out floats [0, 8388608); groupmin (16 MB) = floats [8388608, 12582912)
  unsigned short* zbf = (unsigned short*)out;
  float* groupmin = out + 8388608;

  init_kernel<<<64, 256, 0, stream>>>(counts, loss, tokkey, cnt);
  npsum_sq<<<N_TOK / 16, 256, 0, stream>>>(z, zsum, N_TOK);
  npsum_sq<<<NE / 16, 256, 0, stream>>>(e, esum, NE);
  cvt_bf<<<(NE * DIM) / (256 * 8), 256, 0, stream>>>(e, ebf);
  cvt_bf<<<(N_TOK * DIM) / (256 * 8), 256, 0, stream>>>(z, zbf);
  gemm_groupmin<<<dim3(NE / 128, N_TOK / 128), 256, 0, stream>>>(ebf, zbf, esum, groupmin);
  reduce_groups<<<N_TOK / 4, 256, 0, stream>>>(groupmin, entries, cnt);
  rescan16<<<2048, 256, 0, stream>>>(z, e, zsum, esum, entries, cnt, tokkey);
  writeout<<<N_TOK / 256, 256, 0, stream>>>(tokkey, idx_final, counts, out);
  gather_loss<<<N_TOK / 8, 256, 0, stream>>>(z, e, idx_final, out, loss);
  finalize_kernel<<<1, 256, 0, stream>>>(counts, loss, out);
}

// Round 8
// 795.860 us; speedup vs baseline: 1.2054x; 1.2054x over previous
//
#include <hip/hip_runtime.h>
#include <hip/hip_bf16.h>

#define N_TOK 32768
#define DIM   512
#define NE    2048

#define IDX_OFF  (N_TOK * DIM)
#define LOSS_OFF (IDX_OFF + N_TOK)
#define PERP_OFF (LOSS_OFF + 1)

#define KB(x) ((size_t)(x) << 10)
#define EPS 4e-4f

typedef __attribute__((ext_vector_type(8))) short bf16x8;
typedef __attribute__((ext_vector_type(4))) float f32x4;

__device__ inline unsigned short f2bf(float f) {
  unsigned int x = __float_as_uint(f);
  x = x + 0x7fffu + ((x >> 16) & 1u);
  return (unsigned short)(x >> 16);
}
__device__ inline float bfround(float f) {
  return __uint_as_float((unsigned int)f2bf(f) << 16);
}

__global__ void init_kernel(int* counts) {
  int g = blockIdx.x * 256 + threadIdx.x;
  if (g < NE) counts[g] = 0;
}

// np.sum(x*x, axis=1) exact replication (validated round 4) — do not touch.
__global__ __launch_bounds__(256) void npsum_sq(const float* __restrict__ x,
                                                float* __restrict__ out, int nrows) {
#pragma clang fp contract(off)
  int wave = threadIdx.x >> 6;
  int lane = threadIdx.x & 63;
  int grp = lane >> 4, l = lane & 15;
  int row = blockIdx.x * 16 + wave * 4 + grp;
  if (row >= nrows) return;
  const float* a = x + (size_t)row * DIM;
  float L[4];
  #pragma unroll
  for (int b = 0; b < 4; ++b) {
    const float* p = a + b * 128 + l;
    float q[8];
    #pragma unroll
    for (int j = 0; j < 8; ++j) {
      float t = p[16 * j];
      float s = t * t;
      asm volatile("" : "+v"(s));
      q[j] = s;
    }
    float v = ((q[0] + q[1]) + (q[2] + q[3])) + ((q[4] + q[5]) + (q[6] + q[7]));
    v += __shfl_xor(v, 8);
    v += __shfl_xor(v, 4);
    v += __shfl_xor(v, 2);
    v += __shfl_xor(v, 1);
    L[b] = v;
  }
  if (l == 0) out[row] = (L[0] + L[1]) + (L[2] + L[3]);
}

__global__ __launch_bounds__(256) void cvt_bf(const float* __restrict__ x,
                                              unsigned short* __restrict__ xbf) {
  size_t g = ((size_t)blockIdx.x * 256 + threadIdx.x) * 8;
  float4 a = *(const float4*)(x + g);
  float4 b = *(const float4*)(x + g + 4);
  unsigned short h[8] = {f2bf(a.x), f2bf(a.y), f2bf(a.z), f2bf(a.w),
                         f2bf(b.x), f2bf(b.y), f2bf(b.z), f2bf(b.w)};
  *(uint4*)(xbf + g) = *(uint4*)h;
}

// Stage a 128x64-bf16 tile (16KB) into LDS via global_load_lds width 16.
// LDS dest linear; global source pre-swizzled (involution) so swizzled
// ds_read is conflict-free.
__device__ inline void stage_tile(const unsigned short* __restrict__ gsrc,
                                  unsigned short* lds_base, int w, int l) {
  const int swz_col = ((l & 7) ^ (l >> 3)) * 8;
  const int rsub = l >> 3;
  #pragma unroll
  for (int s4 = 0; s4 < 4; ++s4) {
    int s = w * 4 + s4;
    const unsigned short* g = gsrc + (size_t)(s * 8 + rsub) * DIM + swz_col;
    __builtin_amdgcn_global_load_lds(
        (const __attribute__((address_space(1))) unsigned int*)g,
        (__attribute__((address_space(3))) unsigned int*)(lds_base + s * 512),
        16, 0, 0);
  }
}

// MFMA GEMM. Block = 128 codes x 128 tokens, K=512 in 8 steps of 64,
// double-buffered LDS, 2-phase. Epilogue: per-16-code-group min ->
// groupmin[token][g]. MFMA chunk order identical to validated rounds 6/7.
__global__ __launch_bounds__(256, 2) void gemm_groupmin(
    const unsigned short* __restrict__ ebf, const unsigned short* __restrict__ zbf,
    const float* __restrict__ esum, float* __restrict__ groupmin) {
  __shared__ unsigned short smem[2 * 16384];

  const int tid = threadIdx.x;
  const int cb = blockIdx.x;   // code block (16)
  const int tb = blockIdx.y;   // token block (256)
  const int w = tid >> 6, l = tid & 63;
  const int lr = l & 15, lk = l >> 4;
  const int wrow = (w >> 1) * 64;
  const int wcol = (w & 1) * 64;

  float esr[4][4];
  #pragma unroll
  for (int i = 0; i < 4; ++i)
    #pragma unroll
    for (int q = 0; q < 4; ++q)
      esr[i][q] = esum[cb * 128 + wrow + i * 16 + lk * 4 + q];

  f32x4 acc[4][4];
  #pragma unroll
  for (int i = 0; i < 4; ++i)
    #pragma unroll
    for (int j = 0; j < 4; ++j) acc[i][j] = (f32x4)(0.f);

  const unsigned short* Ag = ebf + (size_t)(cb * 128) * DIM;
  const unsigned short* Bg = zbf + (size_t)(tb * 128) * DIM;

  stage_tile(Ag, &smem[0], w, l);
  stage_tile(Bg, &smem[8192], w, l);
  asm volatile("s_waitcnt vmcnt(0)" ::: "memory");
  __syncthreads();

  for (int kt = 0; kt < 8; ++kt) {
    const int cur = kt & 1;
    if (kt < 7) {
      stage_tile(Ag + (kt + 1) * 64, &smem[(cur ^ 1) * 16384], w, l);
      stage_tile(Bg + (kt + 1) * 64, &smem[(cur ^ 1) * 16384 + 8192], w, l);
    }
    const unsigned short* Ab = &smem[cur * 16384];
    const unsigned short* Bb = Ab + 8192;
    #pragma unroll
    for (int ks = 0; ks < 2; ++ks) {
      bf16x8 a[4], b[4];
      #pragma unroll
      for (int i = 0; i < 4; ++i) {
        int row = wrow + i * 16 + lr;
        a[i] = *(const bf16x8*)&Ab[row * 64 + (((ks * 4 + lk) ^ (lr & 7)) * 8)];
      }
      #pragma unroll
      for (int j = 0; j < 4; ++j) {
        int row = wcol + j * 16 + lr;
        b[j] = *(const bf16x8*)&Bb[row * 64 + (((ks * 4 + lk) ^ (lr & 7)) * 8)];
      }
      #pragma unroll
      for (int i = 0; i < 4; ++i)
        #pragma unroll
        for (int j = 0; j < 4; ++j)
          acc[i][j] = __builtin_amdgcn_mfma_f32_16x16x32_bf16(a[i], b[j], acc[i][j], 0, 0, 0);
    }
    if (kt < 7) {
      asm volatile("s_waitcnt vmcnt(0)" ::: "memory");
      __syncthreads();
    }
  }

  #pragma unroll
  for (int i = 0; i < 4; ++i) {
    const int g = cb * 8 + (wrow >> 4) + i;
    #pragma unroll
    for (int j = 0; j < 4; ++j) {
      float v0 = fmaf(-2.f, acc[i][j][0], esr[i][0]);
      float v1 = fmaf(-2.f, acc[i][j][1], esr[i][1]);
      float v2 = fmaf(-2.f, acc[i][j][2], esr[i][2]);
      float v3 = fmaf(-2.f, acc[i][j][3], esr[i][3]);
      float m = fminf(fminf(v0, v1), fminf(v2, v3));
      m = fminf(m, __shfl_xor(m, 16));
      m = fminf(m, __shfl_xor(m, 32));
      if (lk == 0) {
        int token = tb * 128 + wcol + j * 16 + lr;
        groupmin[(size_t)token * 128 + g] = m;
      }
    }
  }
}

// One wave per token: scan 128 group minima, ballot candidate groups within
// EPS, exact np-replica rescan (16 lanes x 1 code, sequential fmaf chain),
// in-register winner with first-index tie-break. No contended atomics.
__global__ __launch_bounds__(256) void select_exact(
    const float* __restrict__ z, const float* __restrict__ e,
    const float* __restrict__ zsum, const float* __restrict__ esum,
    const float* __restrict__ groupmin,
    int* __restrict__ idx_final, int* __restrict__ counts,
    float* __restrict__ out) {
  int t = blockIdx.x * 4 + (threadIdx.x >> 6);
  int lane = threadIdx.x & 63;
  float g0 = groupmin[(size_t)t * 128 + lane];
  float g1 = groupmin[(size_t)t * 128 + 64 + lane];
  float m = fminf(g0, g1);
  #pragma unroll
  for (int s = 32; s >= 1; s >>= 1) m = fminf(m, __shfl_xor(m, s));
  float lim = m + EPS;
  unsigned long long mm0 = __ballot(g0 <= lim);
  unsigned long long mm1 = __ballot(g1 <= lim);
  float zst = zsum[t];
  const float* zr = z + (size_t)t * DIM;
  float bd = 3.402823466e38f; int bc = 0x7fffffff;

  #pragma unroll 1
  for (int half = 0; half < 2; ++half) {
    unsigned long long mk = half ? mm1 : mm0;
    while (mk) {
      int ga[4]; int np = 0;
      while (mk && np < 4) {
        int b = __ffsll((unsigned long long)mk) - 1;
        mk &= mk - 1;
        ga[np++] = half * 64 + b;
      }
      int sub = lane >> 4;
      bool valid = sub < np;
      int grp = ga[valid ? sub : 0];
      int c = grp * 16 + (lane & 15);
      const float* er = e + (size_t)c * DIM;
      float acc = 0.f;
      for (int k = 0; k < DIM; k += 4) {
        float4 zv = *(const float4*)(zr + k);
        float4 ev = *(const float4*)(er + k);
        acc = fmaf(zv.x, ev.x, acc);
        acc = fmaf(zv.y, ev.y, acc);
        acc = fmaf(zv.z, ev.z, acc);
        acc = fmaf(zv.w, ev.w, acc);
      }
      float s = zst + esum[c];
      float d = s - 2.f * acc;
      if (!valid) { d = 3.402823466e38f; c = 0x7fffffff; }
      if (d < bd || (d == bd && c < bc)) { bd = d; bc = c; }
    }
  }
  #pragma unroll
  for (int s = 32; s >= 1; s >>= 1) {
    float od = __shfl_xor(bd, s); int oc = __shfl_xor(bc, s);
    if (od < bd || (od == bd && oc < bc)) { bd = od; bc = oc; }
  }
  if (lane == 0) {
    idx_final[t] = bc;
    out[IDX_OFF + t] = bfround((float)bc);
    atomicAdd(&counts[bc], 1);   // spread over 2048 addresses
  }
}

// 8 tokens/block, 32 threads/token; per-block loss partial (no atomics).
__global__ __launch_bounds__(256) void gather_loss(
    const float* __restrict__ z, const float* __restrict__ e,
    const int* __restrict__ idx_final, float* __restrict__ out,
    float* __restrict__ lossp) {
  __shared__ float red[4];
  int t = blockIdx.x * 8 + (threadIdx.x >> 5);
  int g = threadIdx.x & 31;
  int idx = idx_final[t] & (NE - 1);
  const float* zr = z + (size_t)t * DIM;
  const float* er = e + (size_t)idx * DIM;
  float* op = out + (size_t)t * DIM;
  float s = 0.f;
  #pragma unroll
  for (int p = 0; p < 4; ++p) {
    int c = p * 128 + g * 4;
    float4 ev = *(const float4*)(er + c);
    float4 zv = *(const float4*)(zr + c);
    float4 ov;
    ov.x = bfround(ev.x); ov.y = bfround(ev.y);
    ov.z = bfround(ev.z); ov.w = bfround(ev.w);
    *(float4*)(op + c) = ov;
    float dx = ev.x - zv.x, dy = ev.y - zv.y, dz2 = ev.z - zv.z, dw = ev.w - zv.w;
    s += dx*dx + dy*dy + dz2*dz2 + dw*dw;
  }
  #pragma unroll
  for (int m = 32; m >= 1; m >>= 1) s += __shfl_xor(s, m);
  if ((threadIdx.x & 63) == 0) red[threadIdx.x >> 6] = s;
  __syncthreads();
  if (threadIdx.x == 0)
    lossp[blockIdx.x] = red[0] + red[1] + red[2] + red[3];
}

__global__ void finalize_kernel(const int* __restrict__ counts,
                                const float* __restrict__ lossp,
                                float* __restrict__ out) {
  __shared__ float red[4], red2[4];
  int tid = threadIdx.x;
  float s = 0.f;
  for (int j = tid; j < NE; j += 256) {
    float p = (float)counts[j] * (1.0f / (float)N_TOK);
    s += p * logf(p + 1e-10f);
  }
  float ls = 0.f;
  for (int j = tid; j < 4096; j += 256) ls += lossp[j];
  #pragma unroll
  for (int m = 32; m >= 1; m >>= 1) {
    s += __shfl_xor(s, m);
    ls += __shfl_xor(ls, m);
  }
  if ((tid & 63) == 0) { red[tid >> 6] = s; red2[tid >> 6] = ls; }
  __syncthreads();
  if (tid == 0) {
    float tot = red[0] + red[1] + red[2] + red[3];
    float lt = red2[0] + red2[1] + red2[2] + red2[3];
    out[PERP_OFF] = bfround(expf(-tot));
    out[LOSS_OFF] = bfround(lt * 1.25f / (float)(N_TOK * DIM));
  }
}

extern "C" void kernel_launch(void* const* d_in, const int* in_sizes, int n_in,
                              void* d_out, int out_size, void* d_ws, size_t ws_size,
                              hipStream_t stream) {
  const float* z = (const float*)d_in[0];
  const float* e = (const float*)d_in[1];
  float* out = (float*)d_out;
  char* ws = (char*)d_ws;

  // workspace (~2.3 MB)
  float*    zsum      = (float*)(ws + KB(0));      // 128 KB
  float*    esum      = (float*)(ws + KB(128));    // 8 KB
  int*      counts    = (int*)(ws + KB(136));      // 8 KB
  float*    lossp     = (float*)(ws + KB(144));    // 16 KB
  int*      idx_final = (int*)(ws + KB(160));      // 128 KB
  unsigned short* ebf = (unsigned short*)(ws + KB(288)); // 2 MB

  // big scratch parked in d_out (overwritten at the end of each launch):
  unsigned short* zbf = (unsigned short*)out;      // 32 MB
  float* groupmin = out + 8388608;                 // 16 MB

  init_kernel<<<8, 256, 0, stream>>>(counts);
  npsum_sq<<<N_TOK / 16, 256, 0, stream>>>(z, zsum, N_TOK);
  npsum_sq<<<NE / 16, 256, 0, stream>>>(e, esum, NE);
  cvt_bf<<<(NE * DIM) / (256 * 8), 256, 0, stream>>>(e, ebf);
  cvt_bf<<<(N_TOK * DIM) / (256 * 8), 256, 0, stream>>>(z, zbf);
  gemm_groupmin<<<dim3(NE / 128, N_TOK / 128), 256, 0, stream>>>(ebf, zbf, esum, groupmin);
  select_exact<<<N_TOK / 4, 256, 0, stream>>>(z, e, zsum, esum, groupmin,
                                              idx_final, counts, out);
  gather_loss<<<N_TOK / 8, 256, 0, stream>>>(z, e, idx_final, out, lossp);
  finalize_kernel<<<1, 256, 0, stream>>>(counts, lossp, out);
}